// Round 2
// baseline (142.204 us; speedup 1.0000x reference)
//
#include <hip/hip_runtime.h>
#include <hip/hip_bf16.h>

#define TSEQ 2048
#define DH   64
#define NBH  32     // B*H = 2*16
#define QT   64     // q rows per block (4 waves x 16)
#define KT   64     // k rows per tile

typedef __attribute__((ext_vector_type(8))) short short8_t;
typedef __attribute__((ext_vector_type(4))) float f32x4;
typedef __attribute__((ext_vector_type(4))) unsigned short ushort4_t;

__device__ __forceinline__ unsigned short f2bf(float f) {
    unsigned int u = __float_as_uint(f);
    return (unsigned short)((u + 0x7fffu + ((u >> 16) & 1u)) >> 16);
}

// byte-offset XOR swizzle for 128B-row LDS tiles (G4: breaks 16-way conflicts)
__device__ __forceinline__ unsigned int swz(unsigned int row, unsigned int cb) {
    return row * 128u + (cb ^ ((row & 7u) << 4));
}

// fp32 -> bf16 (optionally prescaled), 8 elems/thread
__global__ __launch_bounds__(256) void cvt_kernel(const float* __restrict__ src,
                                                  unsigned short* __restrict__ dst,
                                                  float scale, int n8) {
    int i = blockIdx.x * 256 + threadIdx.x;
    if (i >= n8) return;
    const float4* s = reinterpret_cast<const float4*>(src) + (size_t)i * 2;
    float4 a = s[0], b = s[1];
    short8_t o;
    o[0] = (short)f2bf(a.x * scale); o[1] = (short)f2bf(a.y * scale);
    o[2] = (short)f2bf(a.z * scale); o[3] = (short)f2bf(a.w * scale);
    o[4] = (short)f2bf(b.x * scale); o[5] = (short)f2bf(b.y * scale);
    o[6] = (short)f2bf(b.z * scale); o[7] = (short)f2bf(b.w * scale);
    *reinterpret_cast<short8_t*>(dst + (size_t)i * 8) = o;
}

// V [bh][t][d] fp32 -> Vt [bh][d][t] bf16, 64x64 tiles via LDS
__global__ __launch_bounds__(256) void vt_kernel(const float* __restrict__ V,
                                                 unsigned short* __restrict__ Vt) {
    __shared__ float tile[64][65];
    const int bh = blockIdx.y;
    const int t0 = blockIdx.x * 64;
    const int tid = threadIdx.x;
    const float* src = V + ((size_t)bh * TSEQ + t0) * DH;
#pragma unroll
    for (int it = 0; it < 4; ++it) {
        int idx = tid + it * 256;          // float4 units, 1024 total
        int row = idx >> 4;                // t within tile
        int c   = (idx & 15) * 4;          // d
        float4 v = *reinterpret_cast<const float4*>(src + row * DH + c);
        tile[row][c + 0] = v.x; tile[row][c + 1] = v.y;
        tile[row][c + 2] = v.z; tile[row][c + 3] = v.w;
    }
    __syncthreads();
#pragma unroll
    for (int it = 0; it < 4; ++it) {
        int idx = tid + it * 256;
        int d  = idx >> 4;
        int c  = (idx & 15) * 4;           // t within tile
        ushort4_t o;
        o[0] = f2bf(tile[c + 0][d]); o[1] = f2bf(tile[c + 1][d]);
        o[2] = f2bf(tile[c + 2][d]); o[3] = f2bf(tile[c + 3][d]);
        *reinterpret_cast<ushort4_t*>(Vt + ((size_t)bh * DH + d) * TSEQ + t0 + c) = o;
    }
}

// flash attention: one block = 64 q rows of one (b,h); 4 waves x 16 rows
__global__ __launch_bounds__(256) void attn_kernel(const unsigned short* __restrict__ Qb,
                                                   const unsigned short* __restrict__ Kb,
                                                   const unsigned short* __restrict__ Vt,
                                                   const float* __restrict__ mask,
                                                   float* __restrict__ out) {
    __shared__ unsigned short sK[KT * DH];       // [k][d] swizzled, 8KB
    __shared__ unsigned short sV[DH * KT];       // [d][k] swizzled, 8KB
    __shared__ unsigned short sP[4 * 16 * KT];   // per-wave [q][k] swizzled, 8KB

    const int tid  = threadIdx.x;
    const int wave = tid >> 6;
    const int lane = tid & 63;
    const int g    = lane >> 4;
    const int lr   = lane & 15;
    const int bh   = blockIdx.y;
    const int b    = bh >> 4;
    const int q0   = blockIdx.x * QT;

    const float* mp = mask + (size_t)b * TSEQ;
    const float LOG2E = 1.44269504088896340736f;

    // Q A-frags: lane holds Q[q0+wave*16+lr][d = 32c + 8g .. +8] (prescaled by scale*log2e)
    const unsigned short* qrow = Qb + ((size_t)bh * TSEQ + q0 + wave * 16 + lr) * DH;
    short8_t aq0 = *reinterpret_cast<const short8_t*>(qrow + 8 * g);
    short8_t aq1 = *reinterpret_cast<const short8_t*>(qrow + 32 + 8 * g);

    float m_run[4], l_run[4];
    f32x4 oacc[4];
#pragma unroll
    for (int r = 0; r < 4; ++r) { m_run[r] = -1e30f; l_run[r] = 0.f; }
#pragma unroll
    for (int dc = 0; dc < 4; ++dc) oacc[dc] = (f32x4){0.f, 0.f, 0.f, 0.f};

    char* const cK = reinterpret_cast<char*>(sK);
    char* const cV = reinterpret_cast<char*>(sV);
    char* const cP = reinterpret_cast<char*>(sP) + wave * 2048;

    for (int kt = 0; kt < TSEQ / KT; ++kt) {
        const int k0 = kt * KT;
        __syncthreads();
        // stage K tile [64 k][64 d] bf16 (swizzled rows)
#pragma unroll
        for (int it = 0; it < 2; ++it) {
            int idx = tid + it * 256;
            int row = idx >> 3;
            int cb  = (idx & 7) * 16;
            float4 v = *reinterpret_cast<const float4*>(
                reinterpret_cast<const char*>(Kb + ((size_t)bh * TSEQ + k0 + row) * DH) + cb);
            *reinterpret_cast<float4*>(cK + swz(row, cb)) = v;
        }
        // stage V tile [64 d][64 k] bf16 (transposed source, swizzled rows)
#pragma unroll
        for (int it = 0; it < 2; ++it) {
            int idx = tid + it * 256;
            int row = idx >> 3;            // d
            int cb  = (idx & 7) * 16;
            float4 v = *reinterpret_cast<const float4*>(
                reinterpret_cast<const char*>(Vt + ((size_t)bh * DH + row) * TSEQ + k0) + cb);
            *reinterpret_cast<float4*>(cV + swz(row, cb)) = v;
        }
        __syncthreads();

        // S = Q K^T : 4 col-chunks x 2 d-chunks
        f32x4 s[4];
#pragma unroll
        for (int kc = 0; kc < 4; ++kc) {
            s[kc] = (f32x4){0.f, 0.f, 0.f, 0.f};
            short8_t bk0 = *reinterpret_cast<const short8_t*>(cK + swz(16 * kc + lr, 16 * g));
            short8_t bk1 = *reinterpret_cast<const short8_t*>(cK + swz(16 * kc + lr, 64 + 16 * g));
            s[kc] = __builtin_amdgcn_mfma_f32_16x16x32_bf16(aq0, bk0, s[kc], 0, 0, 0);
            s[kc] = __builtin_amdgcn_mfma_f32_16x16x32_bf16(aq1, bk1, s[kc], 0, 0, 0);
        }

        // scores already scale*log2e'd; add mask*log2e; lane holds S[q=4g+r][k=16kc+lr]
        float sv[4][4];
#pragma unroll
        for (int kc = 0; kc < 4; ++kc) {
            float mk = mp[k0 + 16 * kc + lr] * LOG2E;
#pragma unroll
            for (int r = 0; r < 4; ++r) sv[kc][r] = s[kc][r] + mk;
        }
        float mnew[4], alpha[4], psum[4];
#pragma unroll
        for (int r = 0; r < 4; ++r) {
            float t = fmaxf(fmaxf(sv[0][r], sv[1][r]), fmaxf(sv[2][r], sv[3][r]));
            t = fmaxf(t, __shfl_xor(t, 1));
            t = fmaxf(t, __shfl_xor(t, 2));
            t = fmaxf(t, __shfl_xor(t, 4));
            t = fmaxf(t, __shfl_xor(t, 8));
            mnew[r]  = fmaxf(m_run[r], t);
            alpha[r] = exp2f(m_run[r] - mnew[r]);
            psum[r]  = 0.f;
        }
        // P = exp2(S - m), write bf16 to per-wave LDS (wave-local, no barrier)
#pragma unroll
        for (int kc = 0; kc < 4; ++kc) {
#pragma unroll
            for (int r = 0; r < 4; ++r) {
                float p = exp2f(sv[kc][r] - mnew[r]);
                psum[r] += p;
                *reinterpret_cast<unsigned short*>(cP + swz(4 * g + r, (16 * kc + lr) * 2)) = f2bf(p);
            }
        }
#pragma unroll
        for (int r = 0; r < 4; ++r) {
            float t = psum[r];
            t += __shfl_xor(t, 1);
            t += __shfl_xor(t, 2);
            t += __shfl_xor(t, 4);
            t += __shfl_xor(t, 8);
            l_run[r] = l_run[r] * alpha[r] + t;
            m_run[r] = mnew[r];
        }
#pragma unroll
        for (int dc = 0; dc < 4; ++dc) {
#pragma unroll
            for (int r = 0; r < 4; ++r) oacc[dc][r] *= alpha[r];
        }

        // O += P V : 2 k-chunks x 4 d-chunks
#pragma unroll
        for (int kc2 = 0; kc2 < 2; ++kc2) {
            short8_t pa = *reinterpret_cast<const short8_t*>(cP + swz(lr, 64 * kc2 + 16 * g));
#pragma unroll
            for (int dc = 0; dc < 4; ++dc) {
                short8_t bv = *reinterpret_cast<const short8_t*>(cV + swz(16 * dc + lr, 64 * kc2 + 16 * g));
                oacc[dc] = __builtin_amdgcn_mfma_f32_16x16x32_bf16(pa, bv, oacc[dc], 0, 0, 0);
            }
        }
    }

    // epilogue: O[q][d] = acc/l ; lane holds O[q=4g+r][d=16dc+lr]
#pragma unroll
    for (int r = 0; r < 4; ++r) {
        float inv = 1.f / l_run[r];
        float* orow = out + ((size_t)bh * TSEQ + q0 + wave * 16 + 4 * g + r) * DH;
#pragma unroll
        for (int dc = 0; dc < 4; ++dc) orow[16 * dc + lr] = oacc[dc][r] * inv;
    }
}

extern "C" void kernel_launch(void* const* d_in, const int* in_sizes, int n_in,
                              void* d_out, int out_size, void* d_ws, size_t ws_size,
                              hipStream_t stream) {
    const float* Q    = (const float*)d_in[0];
    const float* K    = (const float*)d_in[1];
    const float* V    = (const float*)d_in[2];
    const float* mask = (const float*)d_in[3];
    float* out = (float*)d_out;

    const size_t N = (size_t)NBH * TSEQ * DH;   // 4,194,304 elems per tensor
    unsigned short* Qb = (unsigned short*)d_ws; // needs 3*N*2 = 25.2 MB of ws
    unsigned short* Kb = Qb + N;
    unsigned short* Vt = Kb + N;

    const int n8 = (int)(N / 8);                // 524288 -> 2048 blocks exact
    const float QSCALE = 0.125f * 1.44269504088896340736f; // scale * log2(e)

    hipLaunchKernelGGL(cvt_kernel, dim3(n8 / 256), dim3(256), 0, stream, Q, Qb, QSCALE, n8);
    hipLaunchKernelGGL(cvt_kernel, dim3(n8 / 256), dim3(256), 0, stream, K, Kb, 1.0f, n8);
    hipLaunchKernelGGL(vt_kernel, dim3(TSEQ / 64, NBH), dim3(256), 0, stream, V, Vt);
    hipLaunchKernelGGL(attn_kernel, dim3(TSEQ / QT, NBH), dim3(256), 0, stream,
                       Qb, Kb, Vt, mask, out);
}

// Round 3
// 96.796 us; speedup vs baseline: 1.4691x; 1.4691x over previous
//
#include <hip/hip_runtime.h>
#include <hip/hip_bf16.h>

#define TSEQ 2048
#define DH   64
#define NBH  32     // B*H = 2*16
#define QT   128    // q rows per block: 4 waves x 32
#define KT   64     // k rows per tile

typedef __attribute__((ext_vector_type(8)))  short short8_t;
typedef __attribute__((ext_vector_type(16))) float f32x16;
typedef __attribute__((ext_vector_type(4)))  unsigned short ushort4_t;

#define LOG2E 1.44269504088896340736f

__device__ __forceinline__ unsigned short f2bf(float f) {
    unsigned int u = __float_as_uint(f);
    return (unsigned short)((u + 0x7fffu + ((u >> 16) & 1u)) >> 16);
}

// byte-offset XOR swizzle for 128B-row LDS tiles (G4)
__device__ __forceinline__ unsigned int swz(unsigned int row, unsigned int cb) {
    return row * 128u + (cb ^ ((row & 7u) << 4));
}

__device__ __forceinline__ unsigned int cvtpk(float lo, float hi) {
    unsigned int r;
    asm("v_cvt_pk_bf16_f32 %0, %1, %2" : "=v"(r) : "v"(lo), "v"(hi));
    return r;
}

#define GL2L16(g, l) __builtin_amdgcn_global_load_lds( \
    (__attribute__((address_space(1))) void*)(void*)(g), \
    (__attribute__((address_space(3))) void*)(l), 16, 0, 0)

// fp32 -> bf16 (optionally prescaled), 8 elems/thread
__global__ __launch_bounds__(256) void cvt_kernel(const float* __restrict__ src,
                                                  unsigned short* __restrict__ dst,
                                                  float scale, int n8) {
    int i = blockIdx.x * 256 + threadIdx.x;
    if (i >= n8) return;
    const float4* s = reinterpret_cast<const float4*>(src) + (size_t)i * 2;
    float4 a = s[0], b = s[1];
    short8_t o;
    o[0] = (short)f2bf(a.x * scale); o[1] = (short)f2bf(a.y * scale);
    o[2] = (short)f2bf(a.z * scale); o[3] = (short)f2bf(a.w * scale);
    o[4] = (short)f2bf(b.x * scale); o[5] = (short)f2bf(b.y * scale);
    o[6] = (short)f2bf(b.z * scale); o[7] = (short)f2bf(b.w * scale);
    *reinterpret_cast<short8_t*>(dst + (size_t)i * 8) = o;
}

// V [bh][t][d] fp32 -> Vt [bh][d][t] bf16, 64x64 tiles via LDS
__global__ __launch_bounds__(256) void vt_kernel(const float* __restrict__ V,
                                                 unsigned short* __restrict__ Vt) {
    __shared__ float tile[64][65];
    const int bh = blockIdx.y;
    const int t0 = blockIdx.x * 64;
    const int tid = threadIdx.x;
    const float* src = V + ((size_t)bh * TSEQ + t0) * DH;
#pragma unroll
    for (int it = 0; it < 4; ++it) {
        int idx = tid + it * 256;
        int row = idx >> 4;
        int c   = (idx & 15) * 4;
        float4 v = *reinterpret_cast<const float4*>(src + row * DH + c);
        tile[row][c + 0] = v.x; tile[row][c + 1] = v.y;
        tile[row][c + 2] = v.z; tile[row][c + 3] = v.w;
    }
    __syncthreads();
#pragma unroll
    for (int it = 0; it < 4; ++it) {
        int idx = tid + it * 256;
        int d  = idx >> 4;
        int c  = (idx & 15) * 4;
        ushort4_t o;
        o[0] = f2bf(tile[c + 0][d]); o[1] = f2bf(tile[c + 1][d]);
        o[2] = f2bf(tile[c + 2][d]); o[3] = f2bf(tile[c + 3][d]);
        *reinterpret_cast<ushort4_t*>(Vt + ((size_t)bh * DH + d) * TSEQ + t0 + c) = o;
    }
}

// flash attention: block = 128 q rows of one (b,h); 4 waves x 32 q rows.
// Swapped QK^T (S^T = K.Q^T) with 32x32x16 MFMA; in-register softmax;
// P redistributed to B-frags via cvt_pk + v_permlane32_swap_b32; O^T accum.
__global__ __launch_bounds__(256) void attn_kernel(const unsigned short* __restrict__ Qb,
                                                   const unsigned short* __restrict__ Kb,
                                                   const unsigned short* __restrict__ Vt,
                                                   const float* __restrict__ mask,
                                                   float* __restrict__ out) {
    __shared__ unsigned short sK[KT * DH];   // [k][d] swizzled rows, 8KB
    __shared__ unsigned short sV[DH * KT];   // [d][k] swizzled rows, 8KB
    __shared__ float smsk[TSEQ];             // mask row * log2e, 8KB

    const int tid  = threadIdx.x;
    const int wave = tid >> 6;
    const int lane = tid & 63;
    const int l31  = lane & 31;
    const int hi   = lane >> 5;
    const int bh   = blockIdx.y;
    const int b    = bh >> 4;
    const int q0   = blockIdx.x * QT;

    // stage full mask row (scaled) once per block
    {
        const float4* m4 = reinterpret_cast<const float4*>(mask + (size_t)b * TSEQ);
        float4* s4 = reinterpret_cast<float4*>(smsk);
#pragma unroll
        for (int it = 0; it < 2; ++it) {
            int i = tid + it * 256;
            float4 v = m4[i];
            float4 w; w.x = v.x * LOG2E; w.y = v.y * LOG2E; w.z = v.z * LOG2E; w.w = v.w * LOG2E;
            s4[i] = w;
        }
    }

    // Q B-frags: lane holds Q[q0+32*wave+l31][16*dc + 8*hi + j], j=0..7
    const unsigned short* qrow = Qb + ((size_t)bh * TSEQ + q0 + wave * 32 + l31) * DH;
    short8_t qf[4];
#pragma unroll
    for (int dc = 0; dc < 4; ++dc)
        qf[dc] = *reinterpret_cast<const short8_t*>(qrow + 16 * dc + 8 * hi);

    float m_run = -1e30f, l_run = 0.f;
    f32x16 oacc[2];
#pragma unroll
    for (int db = 0; db < 2; ++db)
#pragma unroll
        for (int r = 0; r < 16; ++r) oacc[db][r] = 0.f;

    char* const cK = reinterpret_cast<char*>(sK);
    char* const cV = reinterpret_cast<char*>(sV);
    const char* gK = reinterpret_cast<const char*>(Kb + (size_t)bh * TSEQ * DH); // 128B rows
    const char* gV = reinterpret_cast<const char*>(Vt + (size_t)bh * DH * TSEQ); // 4096B rows

    for (int kt = 0; kt < TSEQ / KT; ++kt) {
        const int k0 = kt * KT;
        __syncthreads();
        // stage K [64k][64d] and V^T [64d][64k] via global_load_lds,
        // pre-swizzled global source, linear LDS dest (m104/m173 pattern)
#pragma unroll
        for (int it = 0; it < 2; ++it) {
            int idx = tid + it * 256;
            int row = idx >> 3;
            unsigned int cb  = (idx & 7) * 16;
            unsigned int scb = cb ^ ((row & 7u) << 4);
            GL2L16(gK + (size_t)(k0 + row) * 128 + scb, cK + idx * 16);
            GL2L16(gV + (size_t)row * 4096 + (size_t)k0 * 2 + scb, cV + idx * 16);
        }
        __syncthreads();

        // S^T = K . Q^T : 2 k-blocks x 4 d-chunks of 32x32x16
        f32x16 s0, s1;
#pragma unroll
        for (int r = 0; r < 16; ++r) { s0[r] = 0.f; s1[r] = 0.f; }
#pragma unroll
        for (int dc = 0; dc < 4; ++dc) {
            short8_t kf0 = *reinterpret_cast<const short8_t*>(cK + swz(l31,      32 * dc + 16 * hi));
            short8_t kf1 = *reinterpret_cast<const short8_t*>(cK + swz(32 + l31, 32 * dc + 16 * hi));
            s0 = __builtin_amdgcn_mfma_f32_32x32x16_bf16(kf0, qf[dc], s0, 0, 0, 0);
            s1 = __builtin_amdgcn_mfma_f32_32x32x16_bf16(kf1, qf[dc], s1, 0, 0, 0);
        }

        // add mask (k = 32*kb + (reg&3) + 8*(reg>>2) + 4*hi), find tile max
        float sv[2][16];
#pragma unroll
        for (int kb = 0; kb < 2; ++kb) {
#pragma unroll
            for (int rr = 0; rr < 4; ++rr) {
                float4 mv = *reinterpret_cast<const float4*>(&smsk[k0 + 32 * kb + 8 * rr + 4 * hi]);
                const f32x16& s = kb ? s1 : s0;
                sv[kb][4 * rr + 0] = s[4 * rr + 0] + mv.x;
                sv[kb][4 * rr + 1] = s[4 * rr + 1] + mv.y;
                sv[kb][4 * rr + 2] = s[4 * rr + 2] + mv.z;
                sv[kb][4 * rr + 3] = s[4 * rr + 3] + mv.w;
            }
        }
        float tm[16];
#pragma unroll
        for (int i = 0; i < 16; ++i) tm[i] = fmaxf(sv[0][i], sv[1][i]);
#pragma unroll
        for (int st = 8; st > 0; st >>= 1)
#pragma unroll
            for (int i = 0; i < st; ++i) tm[i] = fmaxf(tm[i], tm[i + st]);
        float tmax = fmaxf(tm[0], __shfl_xor(tm[0], 32));

        // T13 defer-max: skip rescale while growth <= 8 (log2 domain)
        if (!__all(tmax - m_run <= 8.0f)) {
            float mnew  = fmaxf(m_run, tmax);
            float alpha = exp2f(m_run - mnew);
            m_run = mnew;
            l_run *= alpha;
#pragma unroll
            for (int db = 0; db < 2; ++db)
#pragma unroll
                for (int r = 0; r < 16; ++r) oacc[db][r] *= alpha;
        }

        // P = exp2(sv - m), row-sum, pack to bf16 pairs
        float p[2][16];
        float ps[16];
#pragma unroll
        for (int i = 0; i < 16; ++i) {
            p[0][i] = exp2f(sv[0][i] - m_run);
            p[1][i] = exp2f(sv[1][i] - m_run);
            ps[i] = p[0][i] + p[1][i];
        }
#pragma unroll
        for (int st = 8; st > 0; st >>= 1)
#pragma unroll
            for (int i = 0; i < st; ++i) ps[i] += ps[i + st];
        l_run += ps[0] + __shfl_xor(ps[0], 32);

        unsigned int pkA[2][4], pkB[2][4];
#pragma unroll
        for (int kb = 0; kb < 2; ++kb)
#pragma unroll
            for (int m = 0; m < 4; ++m) {
                pkA[kb][m] = cvtpk(p[kb][4 * m + 0], p[kb][4 * m + 1]);
                pkB[kb][m] = cvtpk(p[kb][4 * m + 2], p[kb][4 * m + 3]);
            }

        // O^T += V^T . P^T : 4 k-chunks x 2 d-blocks; P B-frags via permlane32_swap
#pragma unroll
        for (int c = 0; c < 4; ++c) {
            const int kb = c >> 1;
            const int me = (2 * c) & 3, mo = (2 * c + 1) & 3;
            unsigned int a0 = pkA[kb][me], a1 = pkA[kb][mo];
            unsigned int b0 = pkB[kb][me], b1 = pkB[kb][mo];
            asm("v_permlane32_swap_b32 %0, %1" : "+v"(a0), "+v"(a1));
            asm("v_permlane32_swap_b32 %0, %1" : "+v"(b0), "+v"(b1));
            union { unsigned int u[4]; short8_t s8; } pf;
            pf.u[0] = a0; pf.u[1] = b0; pf.u[2] = a1; pf.u[3] = b1;
#pragma unroll
            for (int db = 0; db < 2; ++db) {
                short8_t vf = *reinterpret_cast<const short8_t*>(cV + swz(32 * db + l31, 32 * c + 16 * hi));
                oacc[db] = __builtin_amdgcn_mfma_f32_32x32x16_bf16(vf, pf.s8, oacc[db], 0, 0, 0);
            }
        }
    }

    // epilogue: lane holds O^T[d][q=l31]; d = 32*db + 8*rr + 4*hi + c -> float4 stores
    float inv = 1.0f / l_run;
    float* orow = out + ((size_t)bh * TSEQ + q0 + wave * 32 + l31) * DH;
#pragma unroll
    for (int db = 0; db < 2; ++db)
#pragma unroll
        for (int rr = 0; rr < 4; ++rr) {
            float4 v;
            v.x = oacc[db][4 * rr + 0] * inv;
            v.y = oacc[db][4 * rr + 1] * inv;
            v.z = oacc[db][4 * rr + 2] * inv;
            v.w = oacc[db][4 * rr + 3] * inv;
            *reinterpret_cast<float4*>(orow + 32 * db + 8 * rr + 4 * hi) = v;
        }
}

extern "C" void kernel_launch(void* const* d_in, const int* in_sizes, int n_in,
                              void* d_out, int out_size, void* d_ws, size_t ws_size,
                              hipStream_t stream) {
    const float* Q    = (const float*)d_in[0];
    const float* K    = (const float*)d_in[1];
    const float* V    = (const float*)d_in[2];
    const float* mask = (const float*)d_in[3];
    float* out = (float*)d_out;

    const size_t N = (size_t)NBH * TSEQ * DH;
    unsigned short* Qb = (unsigned short*)d_ws;
    unsigned short* Kb = Qb + N;
    unsigned short* Vt = Kb + N;

    const int n8 = (int)(N / 8);
    const float QSCALE = 0.125f * LOG2E;  // scale * log2(e) folded into Q

    hipLaunchKernelGGL(cvt_kernel, dim3(n8 / 256), dim3(256), 0, stream, Q, Qb, QSCALE, n8);
    hipLaunchKernelGGL(cvt_kernel, dim3(n8 / 256), dim3(256), 0, stream, K, Kb, 1.0f, n8);
    hipLaunchKernelGGL(vt_kernel, dim3(TSEQ / 64, NBH), dim3(256), 0, stream, V, Vt);
    hipLaunchKernelGGL(attn_kernel, dim3(TSEQ / QT, NBH), dim3(256), 0, stream,
                       Qb, Kb, Vt, mask, out);
}

// Round 4
// 89.057 us; speedup vs baseline: 1.5968x; 1.0869x over previous
//
#include <hip/hip_runtime.h>
#include <hip/hip_bf16.h>

#define TSEQ 2048
#define DH   64
#define NBH  32      // B*H
#define QT   64      // q rows per block: 2 q-waves x 32
#define KT   32      // k rows per tile per stream
#define NIT  32      // (TSEQ/2) / KT iterations per stream

typedef __attribute__((ext_vector_type(8)))  short short8_t;
typedef __attribute__((ext_vector_type(16))) float f32x16;
typedef __attribute__((ext_vector_type(4)))  unsigned short ushort4_t;

#define LOG2E 1.44269504088896340736f

__device__ __forceinline__ unsigned short f2bf(float f) {
    unsigned int u = __float_as_uint(f);
    return (unsigned short)((u + 0x7fffu + ((u >> 16) & 1u)) >> 16);
}

__device__ __forceinline__ unsigned int cvtpk(float lo, float hi) {
    unsigned int r;
    asm("v_cvt_pk_bf16_f32 %0, %1, %2" : "=v"(r) : "v"(lo), "v"(hi));
    return r;
}

#define GL2L16(g, l) __builtin_amdgcn_global_load_lds( \
    (__attribute__((address_space(1))) void*)(void*)(g), \
    (__attribute__((address_space(3))) void*)(l), 16, 0, 0)

// 128B-row K tiles: swizzle slot = row&7
__device__ __forceinline__ unsigned int kswz(unsigned int row, unsigned int cb) {
    return row * 128u + (cb ^ ((row & 7u) << 4));
}
// 64B-row V tiles: slot = (4*row + ((row>>1)&3)) mod 8 bijective per 8 rows
__device__ __forceinline__ unsigned int vswz(unsigned int row, unsigned int cb) {
    return row * 64u + (cb ^ (((row >> 1) & 3u) << 4));
}

// fp32 -> bf16, 8 elems/thread (used for K)
__global__ __launch_bounds__(256) void cvt_kernel(const float* __restrict__ src,
                                                  unsigned short* __restrict__ dst,
                                                  int n8) {
    int i = blockIdx.x * 256 + threadIdx.x;
    if (i >= n8) return;
    const float4* s = reinterpret_cast<const float4*>(src) + (size_t)i * 2;
    float4 a = s[0], b = s[1];
    short8_t o;
    o[0] = (short)f2bf(a.x); o[1] = (short)f2bf(a.y);
    o[2] = (short)f2bf(a.z); o[3] = (short)f2bf(a.w);
    o[4] = (short)f2bf(b.x); o[5] = (short)f2bf(b.y);
    o[6] = (short)f2bf(b.z); o[7] = (short)f2bf(b.w);
    *reinterpret_cast<short8_t*>(dst + (size_t)i * 8) = o;
}

// V [bh][t][d] fp32 -> Vt [bh][d][t] bf16
__global__ __launch_bounds__(256) void vt_kernel(const float* __restrict__ V,
                                                 unsigned short* __restrict__ Vt) {
    __shared__ float tile[64][65];
    const int bh = blockIdx.y;
    const int t0 = blockIdx.x * 64;
    const int tid = threadIdx.x;
    const float* src = V + ((size_t)bh * TSEQ + t0) * DH;
#pragma unroll
    for (int it = 0; it < 4; ++it) {
        int idx = tid + it * 256;
        int row = idx >> 4;
        int c   = (idx & 15) * 4;
        float4 v = *reinterpret_cast<const float4*>(src + row * DH + c);
        tile[row][c + 0] = v.x; tile[row][c + 1] = v.y;
        tile[row][c + 2] = v.z; tile[row][c + 3] = v.w;
    }
    __syncthreads();
#pragma unroll
    for (int it = 0; it < 4; ++it) {
        int idx = tid + it * 256;
        int d  = idx >> 4;
        int c  = (idx & 15) * 4;
        ushort4_t o;
        o[0] = f2bf(tile[c + 0][d]); o[1] = f2bf(tile[c + 1][d]);
        o[2] = f2bf(tile[c + 2][d]); o[3] = f2bf(tile[c + 3][d]);
        *reinterpret_cast<ushort4_t*>(Vt + ((size_t)bh * DH + d) * TSEQ + t0 + c) = o;
    }
}

// flash attention with in-block split-K:
//   block = 64 q rows; waves 0-1: q-halves of k-stream 0 (k<1024), waves 2-3: k-stream 1.
//   Swapped QK^T (S^T = K.Q^T), 32x32x16 MFMA, in-register softmax, mask via MFMA C-init,
//   double-buffered global_load_lds staging, LDS merge of (m,l,O) partials.
__global__ __launch_bounds__(256, 4) void attn_kernel(const float* __restrict__ Qf,
                                                      const unsigned short* __restrict__ Kb,
                                                      const unsigned short* __restrict__ Vt,
                                                      const float* __restrict__ mask,
                                                      float* __restrict__ out) {
    // LDS: [0,16K) K tiles (buf*2+stream)*4096 ; [16K,32K) V tiles ; [32K,40K) mask f32
    __shared__ char lds[40960];
    float* smsk = reinterpret_cast<float*>(lds + 32768);

    const int tid    = threadIdx.x;
    const int wave   = tid >> 6;
    const int lane   = tid & 63;
    const int l31    = lane & 31;
    const int hi     = lane >> 5;
    const int stream = wave >> 1;   // k-half
    const int qw     = wave & 1;    // q-sub-block

    // bijective XCD swizzle: all 32 q-tiles of a bh land on one XCD (bh>>2)
    const int bid = blockIdx.x;
    const int t   = bid >> 3;
    const int bh  = (bid & 7) * 4 + (t >> 5);
    const int q0  = (t & 31) * QT;
    const int b   = bh >> 4;

    // stage mask row * log2e
    {
        const float4* m4 = reinterpret_cast<const float4*>(mask + (size_t)b * TSEQ);
        float4* s4 = reinterpret_cast<float4*>(smsk);
#pragma unroll
        for (int i = 0; i < 2; ++i) {
            int idx = tid + i * 256;
            float4 v = m4[idx];
            float4 w; w.x = v.x * LOG2E; w.y = v.y * LOG2E; w.z = v.z * LOG2E; w.w = v.w * LOG2E;
            s4[idx] = w;
        }
    }

    // Q B-frags direct from fp32 global (scale*log2e folded)
    const float QS = 0.125f * LOG2E;
    const float* qrow = Qf + ((size_t)bh * TSEQ + q0 + qw * 32 + l31) * DH;
    short8_t qf[4];
#pragma unroll
    for (int dc = 0; dc < 4; ++dc) {
        float4 v0 = *reinterpret_cast<const float4*>(qrow + 16 * dc + 8 * hi);
        float4 v1 = *reinterpret_cast<const float4*>(qrow + 16 * dc + 8 * hi + 4);
        union { unsigned int u[4]; short8_t s; } pk;
        pk.u[0] = cvtpk(v0.x * QS, v0.y * QS);
        pk.u[1] = cvtpk(v0.z * QS, v0.w * QS);
        pk.u[2] = cvtpk(v1.x * QS, v1.y * QS);
        pk.u[3] = cvtpk(v1.z * QS, v1.w * QS);
        qf[dc] = pk.s;
    }

    // per-thread staging source addresses (pre-swizzled global, linear LDS)
    const char* gKc = reinterpret_cast<const char*>(Kb + (size_t)bh * TSEQ * DH);
    const char* gVc = reinterpret_cast<const char*>(Vt + (size_t)bh * DH * TSEQ);
    const unsigned int krow = tid >> 3, kcb = (tid & 7) * 16;
    const unsigned int vrow = tid >> 2, vcb = (tid & 3) * 16;
    const char* srcK0 = gKc + (size_t)krow * 128 + (kcb ^ ((krow & 7u) << 4));
    const char* srcK1 = srcK0 + (size_t)1024 * 128;
    const char* srcV0 = gVc + (size_t)vrow * 4096 + (vcb ^ (((vrow >> 1) & 3u) << 4));
    const char* srcV1 = srcV0 + (size_t)1024 * 2;

    float m_run = -1e30f, l_run = 0.f;
    f32x16 oacc0, oacc1;
#pragma unroll
    for (int r = 0; r < 16; ++r) { oacc0[r] = 0.f; oacc1[r] = 0.f; }

    auto stage = [&](int buf, int it) {
        char* base = lds + buf * 8192 + tid * 16;
        GL2L16(srcK0 + (size_t)it * 4096, base);
        GL2L16(srcK1 + (size_t)it * 4096, base + 4096);
        GL2L16(srcV0 + (size_t)it * 64,   base + 16384);
        GL2L16(srcV1 + (size_t)it * 64,   base + 16384 + 4096);
    };

    auto do_tile = [&](int cur, int it) {
        const char* cK = lds + cur * 8192 + stream * 4096;
        const char* cV = cK + 16384;
        const int k0g = stream * 1024 + it * KT;

        // C-init with mask (k = c + 8rr + 4hi)
        f32x16 s;
#pragma unroll
        for (int rr = 0; rr < 4; ++rr) {
            float4 mv = *reinterpret_cast<const float4*>(&smsk[k0g + 8 * rr + 4 * hi]);
            s[4 * rr + 0] = mv.x; s[4 * rr + 1] = mv.y;
            s[4 * rr + 2] = mv.z; s[4 * rr + 3] = mv.w;
        }
        // S^T = K . Q^T
        __builtin_amdgcn_s_setprio(1);
#pragma unroll
        for (int dc = 0; dc < 4; ++dc) {
            short8_t kf = *reinterpret_cast<const short8_t*>(cK + kswz(l31, 32 * dc + 16 * hi));
            s = __builtin_amdgcn_mfma_f32_32x32x16_bf16(kf, qf[dc], s, 0, 0, 0);
        }
        __builtin_amdgcn_s_setprio(0);

        // tile max (k-reduce: in-lane tree + hi exchange)
        float tm[8];
#pragma unroll
        for (int i = 0; i < 8; ++i) tm[i] = fmaxf(s[i], s[i + 8]);
#pragma unroll
        for (int st = 4; st > 0; st >>= 1)
#pragma unroll
            for (int i = 0; i < st; ++i) tm[i] = fmaxf(tm[i], tm[i + st]);
        float tmax = fmaxf(tm[0], __shfl_xor(tm[0], 32));

        // T13 defer-max
        if (!__all(tmax - m_run <= 8.0f)) {
            float mnew  = fmaxf(m_run, tmax);
            float alpha = exp2f(m_run - mnew);
            m_run = mnew; l_run *= alpha;
#pragma unroll
            for (int r = 0; r < 16; ++r) { oacc0[r] *= alpha; oacc1[r] *= alpha; }
        }

        // P = exp2(s - m), row-sum
        float p[16], ps[8];
#pragma unroll
        for (int i = 0; i < 16; ++i) p[i] = exp2f(s[i] - m_run);
#pragma unroll
        for (int i = 0; i < 8; ++i) ps[i] = p[i] + p[i + 8];
#pragma unroll
        for (int st = 4; st > 0; st >>= 1)
#pragma unroll
            for (int i = 0; i < st; ++i) ps[i] += ps[i + st];
        l_run += ps[0] + __shfl_xor(ps[0], 32);

        // pack P to bf16 pairs
        unsigned int pkA[4], pkB[4];
#pragma unroll
        for (int m = 0; m < 4; ++m) {
            pkA[m] = cvtpk(p[4 * m + 0], p[4 * m + 1]);
            pkB[m] = cvtpk(p[4 * m + 2], p[4 * m + 3]);
        }

        // O^T += V^T . P^T ; P B-frags via permlane32_swap (validated R3 layout)
#pragma unroll
        for (int c = 0; c < 2; ++c) {
            unsigned int a0 = pkA[2 * c], a1 = pkA[2 * c + 1];
            unsigned int b0 = pkB[2 * c], b1 = pkB[2 * c + 1];
            asm("v_permlane32_swap_b32 %0, %1" : "+v"(a0), "+v"(a1));
            asm("v_permlane32_swap_b32 %0, %1" : "+v"(b0), "+v"(b1));
            union { unsigned int u[4]; short8_t s8; } pf;
            pf.u[0] = a0; pf.u[1] = b0; pf.u[2] = a1; pf.u[3] = b1;
            __builtin_amdgcn_s_setprio(1);
            short8_t vf0 = *reinterpret_cast<const short8_t*>(cV + vswz(l31,      32 * c + 16 * hi));
            short8_t vf1 = *reinterpret_cast<const short8_t*>(cV + vswz(32 + l31, 32 * c + 16 * hi));
            oacc0 = __builtin_amdgcn_mfma_f32_32x32x16_bf16(vf0, pf.s8, oacc0, 0, 0, 0);
            oacc1 = __builtin_amdgcn_mfma_f32_32x32x16_bf16(vf1, pf.s8, oacc1, 0, 0, 0);
            __builtin_amdgcn_s_setprio(0);
        }
    };

    // main loop: double-buffered (stage next -> compute cur -> sync drains)
    stage(0, 0);
    __syncthreads();
    for (int it = 0; it < NIT - 1; ++it) {
        stage((it + 1) & 1, it + 1);
        do_tile(it & 1, it);
        __syncthreads();
    }
    do_tile((NIT - 1) & 1, NIT - 1);
    __syncthreads();   // all K/V reads done -> LDS reusable for combine

    // combine the two k-streams (exchange opposite d-half + m,l via LDS)
    f32x16 wv, own;
    if (wave < 2) { wv = oacc1; own = oacc0; }
    else          { wv = oacc0; own = oacc1; }
    {
        char* wp = lds + ((wave < 2) ? (wave * 8192) : (16384 + (wave - 2) * 8192));
#pragma unroll
        for (int i = 0; i < 4; ++i) {
            float4 v; v.x = wv[4 * i]; v.y = wv[4 * i + 1]; v.z = wv[4 * i + 2]; v.w = wv[4 * i + 3];
            *reinterpret_cast<float4*>(wp + lane * 64 + ((i * 16) ^ (((lane >> 1) & 3) << 4))) = v;
        }
        float2* ml = reinterpret_cast<float2*>(lds + 32768 + wave * 256);
        if (hi == 0) ml[l31] = make_float2(m_run, l_run);
    }
    __syncthreads();
    {
        const int pw = wave ^ 2;
        const char* rp = lds + ((pw < 2) ? (pw * 8192) : (16384 + (pw - 2) * 8192));
        float oth[16];
#pragma unroll
        for (int i = 0; i < 4; ++i) {
            float4 v = *reinterpret_cast<const float4*>(rp + lane * 64 + ((i * 16) ^ (((lane >> 1) & 3) << 4)));
            oth[4 * i] = v.x; oth[4 * i + 1] = v.y; oth[4 * i + 2] = v.z; oth[4 * i + 3] = v.w;
        }
        float2 mlb = reinterpret_cast<const float2*>(lds + 32768 + pw * 256)[l31];
        float m  = fmaxf(m_run, mlb.x);
        float aa = exp2f(m_run - m), ab = exp2f(mlb.x - m);
        float l  = aa * l_run + ab * mlb.y;
        float inv = 1.0f / l;
        float* orow = out + ((size_t)bh * TSEQ + q0 + qw * 32 + l31) * DH + 32 * stream;
#pragma unroll
        for (int rr = 0; rr < 4; ++rr) {
            float4 v;
            v.x = (aa * own[4 * rr + 0] + ab * oth[4 * rr + 0]) * inv;
            v.y = (aa * own[4 * rr + 1] + ab * oth[4 * rr + 1]) * inv;
            v.z = (aa * own[4 * rr + 2] + ab * oth[4 * rr + 2]) * inv;
            v.w = (aa * own[4 * rr + 3] + ab * oth[4 * rr + 3]) * inv;
            *reinterpret_cast<float4*>(orow + 8 * rr + 4 * hi) = v;
        }
    }
}

extern "C" void kernel_launch(void* const* d_in, const int* in_sizes, int n_in,
                              void* d_out, int out_size, void* d_ws, size_t ws_size,
                              hipStream_t stream) {
    const float* Q    = (const float*)d_in[0];
    const float* K    = (const float*)d_in[1];
    const float* V    = (const float*)d_in[2];
    const float* mask = (const float*)d_in[3];
    float* out = (float*)d_out;

    const size_t N = (size_t)NBH * TSEQ * DH;
    unsigned short* Kb = (unsigned short*)d_ws;   // 8 MB
    unsigned short* Vt = Kb + N;                  // 8 MB

    const int n8 = (int)(N / 8);
    hipLaunchKernelGGL(cvt_kernel, dim3(n8 / 256), dim3(256), 0, stream, K, Kb, n8);
    hipLaunchKernelGGL(vt_kernel, dim3(TSEQ / 64, NBH), dim3(256), 0, stream, V, Vt);
    hipLaunchKernelGGL(attn_kernel, dim3((TSEQ / QT) * NBH), dim3(256), 0, stream,
                       Q, Kb, Vt, mask, out);
}